// Round 1
// baseline (991.854 us; speedup 1.0000x reference)
//
#include <hip/hip_runtime.h>
#include <math.h>

// dims
#define NPIX   131072   // B*H*W = 32*64*64
#define NOPIX  32768    // B*32*32

// ---------------------------------------------------------------------------
// prep: normalize queries, fold into Wk -> qwk[256][16]; exp(rpe), exp(rpe)*scale
// ---------------------------------------------------------------------------
__global__ __launch_bounds__(256) void prep_kernel(
    const float* __restrict__ query,        // [2][256]
    const float* __restrict__ Wk,           // [256][256]
    const float* __restrict__ rpe_bias,     // [9][16]
    const float* __restrict__ attn_scale_w, // [9][16]
    float* __restrict__ qwk,                // out [256][16]  (D-major, g fastest)
    float* __restrict__ rpe_exp,            // out [9][16]
    float* __restrict__ rpe_scale)          // out [9][16]
{
    __shared__ float qn[16 * 33];       // padded: qn[g*33+d]
    __shared__ float Wt[16][260];       // 16 rows of Wk, padded
    int tid = threadIdx.x;

    // load query into grouped layout: g = qq*8 + h, element d
    for (int i = tid; i < 512; i += 256) {
        int qq  = i >> 8;
        int rem = i & 255;
        int h   = rem >> 5;
        int d   = rem & 31;
        qn[((qq << 3) + h) * 33 + d] = query[i];
    }
    __syncthreads();
    if (tid < 16) {
        float s = 0.f;
        #pragma unroll
        for (int d = 0; d < 32; ++d) { float t = qn[tid * 33 + d]; s += t * t; }
        float inv = 1.0f / ((sqrtf(s) + 1e-6f) * sqrtf(32.0f));
        #pragma unroll
        for (int d = 0; d < 32; ++d) qn[tid * 33 + d] *= inv;
    }
    __syncthreads();

    int g  = tid & 15;       // q*8+h
    int Dl = tid >> 4;       // 0..15
    int h2 = g & 7;
    for (int cc = 0; cc < 16; ++cc) {
        for (int i = tid; i < 16 * 256; i += 256)
            Wt[i >> 8][i & 255] = Wk[cc * 16 * 256 + i];
        __syncthreads();
        float acc = 0.f;
        #pragma unroll
        for (int d = 0; d < 32; ++d)
            acc += qn[g * 33 + d] * Wt[Dl][h2 * 32 + d];
        qwk[(cc * 16 + Dl) * 16 + g] = acc;
        __syncthreads();
    }

    if (tid < 144) {
        float r = expf(rpe_bias[tid]);
        rpe_exp[tid]   = r;
        rpe_scale[tid] = r * attn_scale_w[tid];
    }
}

// ---------------------------------------------------------------------------
// cost_v: per pixel: v[256] = x . Wv  and  cost_exp[16] = exp(x . qwk)
// 64 pixels per block, 256 threads, 4x16 register tile per thread
// ---------------------------------------------------------------------------
__global__ __launch_bounds__(256) void cost_v_kernel(
    const float* __restrict__ x,         // [131072][256]
    const float* __restrict__ Wv,        // [256][256]
    const float* __restrict__ qwk,       // [256][16]
    float* __restrict__ v,               // out [131072][256]
    float* __restrict__ cost_exp)        // out [131072][16]
{
    __shared__ float Xs[64][256];        // exactly 64 KB
    int tid = threadIdx.x;
    size_t pix0 = (size_t)blockIdx.x * 64;
    const float* xb = x + pix0 * 256;

    for (int i = tid * 4; i < 64 * 256; i += 256 * 4)
        *(float4*)&Xs[i >> 8][i & 255] = *(const float4*)&xb[i];
    __syncthreads();

    int tx = tid & 15, ty = tid >> 4;    // tx: col group (16 cols), ty: pixel group (4 px)
    float acc[4][16];
    #pragma unroll
    for (int a = 0; a < 4; ++a)
        #pragma unroll
        for (int c = 0; c < 16; ++c) acc[a][c] = 0.f;

    for (int k = 0; k < 256; k += 4) {
        float4 a4[4];
        #pragma unroll
        for (int a = 0; a < 4; ++a)
            a4[a] = *(const float4*)&Xs[ty * 4 + a][k];
        #pragma unroll
        for (int kk = 0; kk < 4; ++kk) {
            const float4* wr = (const float4*)(Wv + (size_t)(k + kk) * 256 + tx * 16);
            float4 b0 = wr[0], b1 = wr[1], b2 = wr[2], b3 = wr[3];
            float bv[16] = {b0.x,b0.y,b0.z,b0.w, b1.x,b1.y,b1.z,b1.w,
                            b2.x,b2.y,b2.z,b2.w, b3.x,b3.y,b3.z,b3.w};
            #pragma unroll
            for (int a = 0; a < 4; ++a) {
                float av = (kk == 0) ? a4[a].x : (kk == 1) ? a4[a].y
                         : (kk == 2) ? a4[a].z : a4[a].w;
                #pragma unroll
                for (int c = 0; c < 16; ++c)
                    acc[a][c] = fmaf(av, bv[c], acc[a][c]);
            }
        }
    }

    // store v
    #pragma unroll
    for (int a = 0; a < 4; ++a) {
        float4* dst = (float4*)(v + (pix0 + ty * 4 + a) * 256 + tx * 16);
        #pragma unroll
        for (int c4 = 0; c4 < 4; ++c4)
            dst[c4] = make_float4(acc[a][4*c4], acc[a][4*c4+1],
                                  acc[a][4*c4+2], acc[a][4*c4+3]);
    }

    // cost: thread handles g = tid&15, pixels p = (tid>>4) + {0,16,32,48}
    int g2 = tid & 15;
    int pbase = tid >> 4;
    #pragma unroll
    for (int pp = 0; pp < 4; ++pp) {
        int p = pbase + pp * 16;
        float c0 = 0.f, c1 = 0.f, c2 = 0.f, c3 = 0.f;
        for (int k = 0; k < 256; k += 4) {
            float4 xa = *(const float4*)&Xs[p][k];
            c0 = fmaf(xa.x, qwk[(k + 0) * 16 + g2], c0);
            c1 = fmaf(xa.y, qwk[(k + 1) * 16 + g2], c1);
            c2 = fmaf(xa.z, qwk[(k + 2) * 16 + g2], c2);
            c3 = fmaf(xa.w, qwk[(k + 3) * 16 + g2], c3);
        }
        cost_exp[(pix0 + p) * 16 + g2] = expf((c0 + c1) + (c2 + c3));
    }
}

// ---------------------------------------------------------------------------
// conv: one block per output pixel. den + weighted windowed sum of v,
// divide, sum over queries -> write pre-projection into d_out.
// ---------------------------------------------------------------------------
__global__ __launch_bounds__(256) void conv_kernel(
    const float* __restrict__ v,         // [131072][256]
    const float* __restrict__ cost_exp,  // [131072][16]
    const float* __restrict__ rpe_exp,   // [9][16]
    const float* __restrict__ rpe_scale, // [9][16]
    float* __restrict__ out_pre)         // [32768][256]  (= d_out)
{
    __shared__ float ce_s[9][16];
    __shared__ float coef[9][16];
    __shared__ float invden[16];
    __shared__ int   vpix[9];
    int t  = threadIdx.x;
    int op = blockIdx.x;                 // b*1024 + io*32 + jo
    int b  = op >> 10;
    int io = (op >> 5) & 31;
    int jo = op & 31;
    int i0 = io * 2 - 1, j0 = jo * 2 - 1;

    if (t < 144) {
        int w = t >> 4, g = t & 15;
        int ky = w / 3, kx = w - ky * 3;
        int i = i0 + ky, j = j0 + kx;
        float ce = 0.f;
        if ((unsigned)i < 64u && (unsigned)j < 64u)
            ce = cost_exp[((size_t)(((b << 6) + i) << 6) + j) * 16 + g];
        ce_s[w][g] = ce;
        coef[w][g] = ce * rpe_scale[w * 16 + g];
    }
    if (t < 9) {
        int ky = t / 3, kx = t - ky * 3;
        int i = i0 + ky, j = j0 + kx;
        vpix[t] = ((unsigned)i < 64u && (unsigned)j < 64u)
                    ? (((b << 6) + i) << 6) + j : -1;
    }
    __syncthreads();
    if (t < 16) {
        float d = 0.f;
        #pragma unroll
        for (int w = 0; w < 9; ++w) d += rpe_exp[w * 16 + t] * ce_s[w][t];
        invden[t] = 1.0f / d;
    }
    __syncthreads();

    int h = t >> 5;                      // head
    float s0 = 0.f, s1 = 0.f;
    #pragma unroll
    for (int w = 0; w < 9; ++w) {
        int pw = vpix[w];
        if (pw >= 0) {
            float vv = v[(size_t)pw * 256 + t];
            s0 = fmaf(coef[w][h],     vv, s0);   // q = 0
            s1 = fmaf(coef[w][8 + h], vv, s1);   // q = 1
        }
    }
    out_pre[(size_t)op * 256 + t] = s0 * invden[h] + s1 * invden[8 + h];
}

// ---------------------------------------------------------------------------
// out_gemm: in-place  out[m][:] = out[m][:] . Wo   (each block owns its rows)
// ---------------------------------------------------------------------------
__global__ __launch_bounds__(256) void out_gemm_kernel(
    const float* __restrict__ Wo,        // [256][256]
    float* __restrict__ out)             // [32768][256], in-place
{
    __shared__ float Xs[64][256];
    int tid = threadIdx.x;
    size_t row0 = (size_t)blockIdx.x * 64;
    float* xb = out + row0 * 256;

    for (int i = tid * 4; i < 64 * 256; i += 256 * 4)
        *(float4*)&Xs[i >> 8][i & 255] = *(const float4*)&xb[i];
    __syncthreads();

    int tx = tid & 15, ty = tid >> 4;
    float acc[4][16];
    #pragma unroll
    for (int a = 0; a < 4; ++a)
        #pragma unroll
        for (int c = 0; c < 16; ++c) acc[a][c] = 0.f;

    for (int k = 0; k < 256; k += 4) {
        float4 a4[4];
        #pragma unroll
        for (int a = 0; a < 4; ++a)
            a4[a] = *(const float4*)&Xs[ty * 4 + a][k];
        #pragma unroll
        for (int kk = 0; kk < 4; ++kk) {
            const float4* wr = (const float4*)(Wo + (size_t)(k + kk) * 256 + tx * 16);
            float4 b0 = wr[0], b1 = wr[1], b2 = wr[2], b3 = wr[3];
            float bv[16] = {b0.x,b0.y,b0.z,b0.w, b1.x,b1.y,b1.z,b1.w,
                            b2.x,b2.y,b2.z,b2.w, b3.x,b3.y,b3.z,b3.w};
            #pragma unroll
            for (int a = 0; a < 4; ++a) {
                float av = (kk == 0) ? a4[a].x : (kk == 1) ? a4[a].y
                         : (kk == 2) ? a4[a].z : a4[a].w;
                #pragma unroll
                for (int c = 0; c < 16; ++c)
                    acc[a][c] = fmaf(av, bv[c], acc[a][c]);
            }
        }
    }

    #pragma unroll
    for (int a = 0; a < 4; ++a) {
        float4* dst = (float4*)(out + (row0 + ty * 4 + a) * 256 + tx * 16);
        #pragma unroll
        for (int c4 = 0; c4 < 4; ++c4)
            dst[c4] = make_float4(acc[a][4*c4], acc[a][4*c4+1],
                                  acc[a][4*c4+2], acc[a][4*c4+3]);
    }
}

// ---------------------------------------------------------------------------
extern "C" void kernel_launch(void* const* d_in, const int* in_sizes, int n_in,
                              void* d_out, int out_size, void* d_ws, size_t ws_size,
                              hipStream_t stream)
{
    const float* x     = (const float*)d_in[0];
    const float* query = (const float*)d_in[1];
    const float* Wk    = (const float*)d_in[2];
    const float* Wv    = (const float*)d_in[3];
    const float* rpe   = (const float*)d_in[4];
    const float* asw   = (const float*)d_in[5];
    const float* Wo    = (const float*)d_in[6];
    float* out = (float*)d_out;

    float* ws        = (float*)d_ws;
    float* qwk       = ws;                       // 4096
    float* rpe_exp   = ws + 4096;                // 144
    float* rpe_scale = ws + 4096 + 144;          // 144
    float* cost_exp  = ws + 4608;                // 131072*16 = 2,097,152
    float* v         = cost_exp + 2097152;       // 131072*256 = 33,554,432
    // total ws use: ~142.6 MB

    prep_kernel<<<dim3(1), dim3(256), 0, stream>>>(query, Wk, rpe, asw,
                                                   qwk, rpe_exp, rpe_scale);
    cost_v_kernel<<<dim3(NPIX / 64), dim3(256), 0, stream>>>(x, Wv, qwk, v, cost_exp);
    conv_kernel<<<dim3(NOPIX), dim3(256), 0, stream>>>(v, cost_exp, rpe_exp, rpe_scale, out);
    out_gemm_kernel<<<dim3(NOPIX / 64), dim3(256), 0, stream>>>(Wo, out);
}

// Round 2
// 421.280 us; speedup vs baseline: 2.3544x; 2.3544x over previous
//
#include <hip/hip_runtime.h>
#include <math.h>

// dims
#define NPIX   131072   // B*H*W = 32*64*64
#define NOPIX  32768    // B*32*32

typedef __attribute__((ext_vector_type(8))) short bf16x8;   // 8 bf16 = 4 VGPRs
typedef __attribute__((ext_vector_type(4))) short short4v;  // 8B
typedef __attribute__((ext_vector_type(4))) float floatx4;

static __device__ __forceinline__ short f2bf(float f) {
    union { float f; unsigned u; } a; a.f = f;
    unsigned r = a.u + 0x7fffu + ((a.u >> 16) & 1u);   // RNE
    return (short)(r >> 16);
}
static __device__ __forceinline__ float bf2f(short s) {
    union { unsigned u; float f; } c; c.u = ((unsigned)(unsigned short)s) << 16;
    return c.f;
}

// ---------------------------------------------------------------------------
// prep: normalize queries, fold into Wk -> qwk[256][16]; exp(rpe), exp(rpe)*scale
// ---------------------------------------------------------------------------
__global__ __launch_bounds__(256) void prep_kernel(
    const float* __restrict__ query,        // [2][256]
    const float* __restrict__ Wk,           // [256][256]
    const float* __restrict__ rpe_bias,     // [9][16]
    const float* __restrict__ attn_scale_w, // [9][16]
    float* __restrict__ qwk,                // out [256][16]  (D-major, g fastest)
    float* __restrict__ rpe_exp,            // out [9][16]
    float* __restrict__ rpe_scale)          // out [9][16]
{
    __shared__ float qn[16 * 33];
    __shared__ float Wt[16][260];
    int tid = threadIdx.x;

    for (int i = tid; i < 512; i += 256) {
        int qq  = i >> 8;
        int rem = i & 255;
        int h   = rem >> 5;
        int d   = rem & 31;
        qn[((qq << 3) + h) * 33 + d] = query[i];
    }
    __syncthreads();
    if (tid < 16) {
        float s = 0.f;
        #pragma unroll
        for (int d = 0; d < 32; ++d) { float t = qn[tid * 33 + d]; s += t * t; }
        float inv = 1.0f / ((sqrtf(s) + 1e-6f) * sqrtf(32.0f));
        #pragma unroll
        for (int d = 0; d < 32; ++d) qn[tid * 33 + d] *= inv;
    }
    __syncthreads();

    int g  = tid & 15;
    int Dl = tid >> 4;
    int h2 = g & 7;
    for (int cc = 0; cc < 16; ++cc) {
        for (int i = tid; i < 16 * 256; i += 256)
            Wt[i >> 8][i & 255] = Wk[cc * 16 * 256 + i];
        __syncthreads();
        float acc = 0.f;
        #pragma unroll
        for (int d = 0; d < 32; ++d)
            acc += qn[g * 33 + d] * Wt[Dl][h2 * 32 + d];
        qwk[(cc * 16 + Dl) * 16 + g] = acc;
        __syncthreads();
    }

    if (tid < 144) {
        float r = expf(rpe_bias[tid]);
        rpe_exp[tid]   = r;
        rpe_scale[tid] = r * attn_scale_w[tid];
    }
}

// ---------------------------------------------------------------------------
// pack B matrices into MFMA b-frag order:
// Bp[(((nt*8)+kc)*64 + lane)*8 + j] = B[kc*32 + (lane>>4)*8 + j][nt*16 + (lane&15)]
// ---------------------------------------------------------------------------
__global__ __launch_bounds__(256) void pack_bv_kernel(
    const float* __restrict__ Wv, const float* __restrict__ qwk,
    short* __restrict__ Bv)
{
    int id = blockIdx.x * 256 + threadIdx.x;          // 17*8*64*8 = 69632
    if (id >= 69632) return;
    int j = id & 7, lane = (id >> 3) & 63, kc = (id >> 9) & 7, nt = id >> 12;
    int k = kc * 32 + ((lane >> 4) << 3) + j;
    int n = nt * 16 + (lane & 15);
    float val = (n < 256) ? Wv[k * 256 + n] : qwk[k * 16 + (n - 256)];
    Bv[id] = f2bf(val);
}

__global__ __launch_bounds__(256) void pack_bo_kernel(
    const float* __restrict__ Wo, short* __restrict__ Bo)
{
    int id = blockIdx.x * 256 + threadIdx.x;          // 16*8*64*8 = 65536
    if (id >= 65536) return;
    int j = id & 7, lane = (id >> 3) & 63, kc = (id >> 9) & 7, nt = id >> 12;
    int k = kc * 32 + ((lane >> 4) << 3) + j;
    int n = nt * 16 + (lane & 15);
    Bo[id] = f2bf(Wo[k * 256 + n]);
}

// ---------------------------------------------------------------------------
// vcost: MFMA GEMM  C[64 x 272] = Xtile[64 x 256] * [Wv | qwk]
// cols 0..255 -> v (bf16), cols 256..271 -> cost_exp = exp(.) (fp32)
// ---------------------------------------------------------------------------
__global__ __launch_bounds__(256, 3) void vcost_mfma_kernel(
    const float* __restrict__ x,      // [131072][256] fp32
    const short* __restrict__ Bv,     // packed [17][8][64][8] bf16
    short* __restrict__ v,            // out [131072][256] bf16
    float* __restrict__ cost_exp)     // out [131072][16] fp32
{
    __shared__ short Xs[64][272];     // 544B rows: 16B-aligned, 34.8 KB
    int tid = threadIdx.x;
    size_t pix0 = (size_t)blockIdx.x * 64;
    const float* xb = x + pix0 * 256;

    // stage fp32 -> bf16 LDS, coalesced float4 reads
    #pragma unroll
    for (int i = 0; i < 16; ++i) {
        int idx = tid * 4 + i * 1024;
        float4 f = *(const float4*)&xb[idx];
        short4v s;
        s.x = f2bf(f.x); s.y = f2bf(f.y); s.z = f2bf(f.z); s.w = f2bf(f.w);
        *(short4v*)&Xs[idx >> 8][idx & 255] = s;
    }
    __syncthreads();

    int lane = tid & 63, w = tid >> 6;
    int m16 = lane & 15, quad = lane >> 4;

    bf16x8 af[8];
    #pragma unroll
    for (int kc = 0; kc < 8; ++kc)
        af[kc] = *(const bf16x8*)&Xs[w * 16 + m16][kc * 32 + quad * 8];

    floatx4 acc[17];
    #pragma unroll
    for (int nt = 0; nt < 17; ++nt) acc[nt] = (floatx4){0.f, 0.f, 0.f, 0.f};

    const short* bp = Bv + (size_t)lane * 8;
    #pragma unroll
    for (int kc = 0; kc < 8; ++kc) {
        #pragma unroll
        for (int nt = 0; nt < 17; ++nt) {
            bf16x8 b = *(const bf16x8*)(bp + (size_t)(nt * 8 + kc) * 512);
            acc[nt] = __builtin_amdgcn_mfma_f32_16x16x32_bf16(af[kc], b, acc[nt], 0, 0, 0);
        }
    }

    // epilogue: C/D layout col=lane&15, row=quad*4+reg
    int mbase = w * 16 + quad * 4;
    #pragma unroll
    for (int nt = 0; nt < 16; ++nt) {
        int col = nt * 16 + m16;
        #pragma unroll
        for (int r = 0; r < 4; ++r)
            v[(pix0 + mbase + r) * 256 + col] = f2bf(acc[nt][r]);
    }
    #pragma unroll
    for (int r = 0; r < 4; ++r)
        cost_exp[(pix0 + mbase + r) * 16 + m16] = expf(acc[16][r]);
}

// ---------------------------------------------------------------------------
// conv: one block per output pixel; windowed weighted sum of bf16 v,
// divide by den, sum over queries -> bf16 out_pre
// ---------------------------------------------------------------------------
__global__ __launch_bounds__(256) void conv_kernel(
    const short* __restrict__ v,         // [131072][256] bf16
    const float* __restrict__ cost_exp,  // [131072][16]
    const float* __restrict__ rpe_exp,   // [9][16]
    const float* __restrict__ rpe_scale, // [9][16]
    short* __restrict__ out_pre)         // [32768][256] bf16
{
    __shared__ float ce_s[9][16];
    __shared__ float coef[9][16];
    __shared__ float invden[16];
    __shared__ int   vpix[9];
    int t  = threadIdx.x;
    int op = blockIdx.x;                 // b*1024 + io*32 + jo
    int b  = op >> 10;
    int io = (op >> 5) & 31;
    int jo = op & 31;
    int i0 = io * 2 - 1, j0 = jo * 2 - 1;

    if (t < 144) {
        int w = t >> 4, g = t & 15;
        int ky = w / 3, kx = w - ky * 3;
        int i = i0 + ky, j = j0 + kx;
        float ce = 0.f;
        if ((unsigned)i < 64u && (unsigned)j < 64u)
            ce = cost_exp[((size_t)(((b << 6) + i) << 6) + j) * 16 + g];
        ce_s[w][g] = ce;
        coef[w][g] = ce * rpe_scale[w * 16 + g];
    }
    if (t < 9) {
        int ky = t / 3, kx = t - ky * 3;
        int i = i0 + ky, j = j0 + kx;
        vpix[t] = ((unsigned)i < 64u && (unsigned)j < 64u)
                    ? (((b << 6) + i) << 6) + j : -1;
    }
    __syncthreads();
    if (t < 16) {
        float d = 0.f;
        #pragma unroll
        for (int w = 0; w < 9; ++w) d += rpe_exp[w * 16 + t] * ce_s[w][t];
        invden[t] = 1.0f / d;
    }
    __syncthreads();

    int h = t >> 5;
    float s0 = 0.f, s1 = 0.f;
    #pragma unroll
    for (int w = 0; w < 9; ++w) {
        int pw = vpix[w];
        if (pw >= 0) {
            float vv = bf2f(v[(size_t)pw * 256 + t]);
            s0 = fmaf(coef[w][h],     vv, s0);
            s1 = fmaf(coef[w][8 + h], vv, s1);
        }
    }
    out_pre[(size_t)op * 256 + t] = f2bf(s0 * invden[h] + s1 * invden[8 + h]);
}

// ---------------------------------------------------------------------------
// out_mfma: out[32768 x 256] = out_pre(bf16) * Wo(packed bf16), fp32 out
// ---------------------------------------------------------------------------
__global__ __launch_bounds__(256, 3) void out_mfma_kernel(
    const short* __restrict__ Ap,     // [32768][256] bf16
    const short* __restrict__ Bo,     // packed [16][8][64][8] bf16
    float* __restrict__ out)          // [32768][256] fp32
{
    __shared__ short Xs[64][272];
    int tid = threadIdx.x;
    size_t row0 = (size_t)blockIdx.x * 64;
    const short* ab = Ap + row0 * 256;

    #pragma unroll
    for (int i = 0; i < 8; ++i) {
        int idx = tid * 8 + i * 2048;          // bf16 elements, 16B chunks
        *(bf16x8*)&Xs[idx >> 8][idx & 255] = *(const bf16x8*)&ab[idx];
    }
    __syncthreads();

    int lane = tid & 63, w = tid >> 6;
    int m16 = lane & 15, quad = lane >> 4;

    bf16x8 af[8];
    #pragma unroll
    for (int kc = 0; kc < 8; ++kc)
        af[kc] = *(const bf16x8*)&Xs[w * 16 + m16][kc * 32 + quad * 8];

    floatx4 acc[16];
    #pragma unroll
    for (int nt = 0; nt < 16; ++nt) acc[nt] = (floatx4){0.f, 0.f, 0.f, 0.f};

    const short* bp = Bo + (size_t)lane * 8;
    #pragma unroll
    for (int kc = 0; kc < 8; ++kc) {
        #pragma unroll
        for (int nt = 0; nt < 16; ++nt) {
            bf16x8 b = *(const bf16x8*)(bp + (size_t)(nt * 8 + kc) * 512);
            acc[nt] = __builtin_amdgcn_mfma_f32_16x16x32_bf16(af[kc], b, acc[nt], 0, 0, 0);
        }
    }

    int mbase = w * 16 + quad * 4;
    #pragma unroll
    for (int nt = 0; nt < 16; ++nt) {
        int col = nt * 16 + m16;
        #pragma unroll
        for (int r = 0; r < 4; ++r)
            out[(row0 + mbase + r) * 256 + col] = acc[nt][r];
    }
}

// ---------------------------------------------------------------------------
extern "C" void kernel_launch(void* const* d_in, const int* in_sizes, int n_in,
                              void* d_out, int out_size, void* d_ws, size_t ws_size,
                              hipStream_t stream)
{
    const float* x     = (const float*)d_in[0];
    const float* query = (const float*)d_in[1];
    const float* Wk    = (const float*)d_in[2];
    const float* Wv    = (const float*)d_in[3];
    const float* rpe   = (const float*)d_in[4];
    const float* asw   = (const float*)d_in[5];
    const float* Wo    = (const float*)d_in[6];
    float* out = (float*)d_out;

    float* ws        = (float*)d_ws;
    float* qwk       = ws;                        // 4096 f
    float* rpe_exp   = ws + 4096;                 // 144 f
    float* rpe_scale = ws + 4240;                 // 144 f
    short* Bv        = (short*)(ws + 4608);       // 69632 bf16 = 34816 f
    short* Bo        = (short*)(ws + 39424);      // 65536 bf16 = 32768 f
    float* cost_exp  = ws + 72192;                // 2,097,152 f
    short* v         = (short*)(ws + 2169344);    // 33,554,432 bf16 = 16,777,216 f
    short* out_pre   = (short*)(ws + 18946560);   // 8,388,608 bf16 = 4,194,304 f
    // total ws use: ~92.6 MB

    prep_kernel<<<dim3(1), dim3(256), 0, stream>>>(query, Wk, rpe, asw,
                                                   qwk, rpe_exp, rpe_scale);
    pack_bv_kernel<<<dim3(272), dim3(256), 0, stream>>>(Wv, qwk, Bv);
    pack_bo_kernel<<<dim3(256), dim3(256), 0, stream>>>(Wo, Bo);
    vcost_mfma_kernel<<<dim3(NPIX / 64), dim3(256), 0, stream>>>(x, Bv, v, cost_exp);
    conv_kernel<<<dim3(NOPIX), dim3(256), 0, stream>>>(v, cost_exp, rpe_exp, rpe_scale, out_pre);
    out_mfma_kernel<<<dim3(NOPIX / 64), dim3(256), 0, stream>>>(out_pre, Bo, out);
}